// Round 14
// baseline (2488.554 us; speedup 1.0000x reference)
//
#include <hip/hip_runtime.h>
#include <math.h>

#define BATCH 4096
#define NIN   4096
#define NOUT  4096

#define BM 128
#define BN 64
#define BK 32
#define NSTAGE (NIN / BK)        // 128
// R9-verified ACID ORDER (frozen): [512x8] k-panels, single ascending fmaf
// chain, fold every 16 stages, f32 epilogue. BASE on MFMA pipe (R13-verified).

typedef __attribute__((ext_vector_type(8))) short bf16x8;
typedef __attribute__((ext_vector_type(8))) unsigned short u16x8;
typedef __attribute__((ext_vector_type(4))) float f32x4;

__device__ __forceinline__ float2 compute_terms(float xv) {
    float h  = (float)exp10(-(double)xv);
    float oh = 1e-14f / h;
    return make_float2(h * 0.1f, oh * 0.1f);
}
__device__ __forceinline__ unsigned short bf16_rne(float v) {
    unsigned int b = __float_as_uint(v);
    return (unsigned short)((b + 0x7FFFu + ((b >> 16) & 1u)) >> 16);
}
__device__ __forceinline__ float signf_of(float wv) {
    return (wv > 0.f) ? 1.f : ((wv < 0.f) ? -1.f : 0.f);
}
__device__ __forceinline__ unsigned short signbf16_of(float wv) {
    return (wv > 0.f) ? 0x3F80u : ((wv < 0.f) ? 0xBF80u : 0u);
}

// --- precompute A: acid f32 TRANSPOSED AaT[k][m] (LDS-tiled) + base bf16 Ab[m][k] ---
__global__ __launch_bounds__(256) void precompute_A(const float* __restrict__ x,
                                                    float* __restrict__ aaT,
                                                    unsigned short* __restrict__ ab) {
    __shared__ float tile[64][65];
    const int m0 = blockIdx.y * 64, k0 = blockIdx.x * 64;
    const int tid = threadIdx.x;
    #pragma unroll
    for (int it = 0; it < 4; ++it) {
        int idx = tid + it * 256;
        int row = idx >> 4, q = idx & 15;
        float4 xv = *(const float4*)(x + (size_t)(m0 + row) * NIN + k0 + q * 4);
        float2 t0 = compute_terms(xv.x), t1 = compute_terms(xv.y),
               t2 = compute_terms(xv.z), t3 = compute_terms(xv.w);
        *(ushort4*)(ab + (size_t)(m0 + row) * NIN + k0 + q * 4) =
            make_ushort4(bf16_rne(t0.y), bf16_rne(t1.y), bf16_rne(t2.y), bf16_rne(t3.y));
        tile[row][q * 4 + 0] = t0.x; tile[row][q * 4 + 1] = t1.x;
        tile[row][q * 4 + 2] = t2.x; tile[row][q * 4 + 3] = t3.x;
    }
    __syncthreads();
    #pragma unroll
    for (int it = 0; it < 4; ++it) {
        int idx = tid + it * 256;
        int krow = idx >> 4, q = idx & 15;
        float4 v = make_float4(tile[q * 4 + 0][krow], tile[q * 4 + 1][krow],
                               tile[q * 4 + 2][krow], tile[q * 4 + 3][krow]);
        *(float4*)(aaT + (size_t)(k0 + krow) * NIN + m0 + q * 4) = v;
    }
}

// --- precompute W: sign bf16 TRANSPOSED signT[n][k] (LDS-tiled) ---
__global__ __launch_bounds__(256) void precompute_signT(const float* __restrict__ w,
                                                        unsigned short* __restrict__ sT) {
    __shared__ unsigned short tile[64][68];
    const int k0 = blockIdx.y * 64, n0 = blockIdx.x * 64;
    const int tid = threadIdx.x;
    #pragma unroll
    for (int it = 0; it < 4; ++it) {
        int idx = tid + it * 256;
        int krow = idx >> 4, q = idx & 15;
        float4 wv = *(const float4*)(w + (size_t)(k0 + krow) * NOUT + n0 + q * 4);
        *(ushort4*)&tile[krow][q * 4] =
            make_ushort4(signbf16_of(wv.x), signbf16_of(wv.y), signbf16_of(wv.z), signbf16_of(wv.w));
    }
    __syncthreads();
    #pragma unroll
    for (int it = 0; it < 2; ++it) {
        int idx = tid + it * 256;
        int n = idx >> 3, kc = idx & 7;
        u16x8 v;
        #pragma unroll
        for (int j = 0; j < 8; ++j) v[j] = tile[kc * 8 + j][n];
        *(u16x8*)(sT + (size_t)(n0 + n) * NIN + k0 + kc * 8) = v;
    }
}

// LDS plan (union, 40960 B):
//   As_acid [32][132] f32 @0      (16896)  acid A [k][m], rows 528B 16B-aligned
//   Bs      [32][68]  f32 @16896  (8704)   sign(W) f32 [k][c]
//   baseA   [128][40] u16 @25600  (10240)  base A bf16 [m][k]
//   Bt      [64][40]  u16 @35840  (5120)   sign bf16 [n][k]
//   Bout    [128][68] f32 @0      (34816)  base result (post-loop reuse)
#define OFF_BS 16896
#define OFF_BA 25600
#define OFF_BT 35840

__global__ __launch_bounds__(256, 2) void acid_gemm_hyb(const float* __restrict__ AaT,
                                                        const unsigned short* __restrict__ Ab,
                                                        const unsigned short* __restrict__ SignT,
                                                        const float* __restrict__ W,
                                                        float* __restrict__ out) {
    __shared__ __align__(16) char smem[40960];
    float*          As_acid = (float*)smem;
    float*          Bs      = (float*)(smem + OFF_BS);
    unsigned short* baseA   = (unsigned short*)(smem + OFF_BA);
    unsigned short* Bt      = (unsigned short*)(smem + OFF_BT);
    float*          Bout    = (float*)smem;

    const int tid  = threadIdx.x;
    const int tx   = tid & 15;
    const int ty   = tid >> 4;
    const int lane = tid & 63;
    const int wv   = tid >> 6;
    const int g    = lane >> 4;
    const int r16  = lane & 15;
    const int bm0  = blockIdx.y * BM;
    const int bn0  = blockIdx.x * BN;

    float ma[8][4] = {}, ca[8][4] = {};
    f32x4 acc[2][4] = {};

    float4 areg[4];   // acid A: k-row tid>>3, m-quads (tid&7)+8r  (from AaT)
    u16x8  breg[2];   // base A: rows (tid>>2)+64r, chunk tid&3    (from Ab)
    float4 wreg[2];   // W: k rows (tid>>4)+16r, col-quad tid&15
    u16x8  btreg;     // signT: n-row tid>>2, chunk tid&3

    #define ISSUE_LOADS(s)                                                         \
        {                                                                          \
            const int k0_ = (s) * BK;                                              \
            _Pragma("unroll")                                                      \
            for (int r = 0; r < 4; ++r)                                            \
                areg[r] = *(const float4*)(AaT +                                   \
                    (size_t)(k0_ + (tid >> 3)) * NIN + bm0 + ((tid & 7) + 8 * r) * 4);\
            _Pragma("unroll")                                                      \
            for (int r = 0; r < 2; ++r)                                            \
                breg[r] = *(const u16x8*)(Ab +                                     \
                    (size_t)(bm0 + (tid >> 2) + 64 * r) * NIN + k0_ + (tid & 3) * 8);\
            _Pragma("unroll")                                                      \
            for (int r = 0; r < 2; ++r)                                            \
                wreg[r] = *(const float4*)(W +                                     \
                    (size_t)(k0_ + (tid >> 4) + 16 * r) * NOUT + bn0 + (tid & 15) * 4);\
            btreg = *(const u16x8*)(SignT +                                        \
                    (size_t)(bn0 + (tid >> 2)) * NIN + k0_ + (tid & 3) * 8);       \
        }

    #define WRITE_LDS()                                                            \
        {                                                                          \
            _Pragma("unroll")                                                      \
            for (int r = 0; r < 4; ++r)                                            \
                *(float4*)&As_acid[(tid >> 3) * 132 + ((tid & 7) + 8 * r) * 4] = areg[r];\
            _Pragma("unroll")                                                      \
            for (int r = 0; r < 2; ++r)                                            \
                *(u16x8*)&baseA[((tid >> 2) + 64 * r) * 40 + (tid & 3) * 8] = breg[r];\
            _Pragma("unroll")                                                      \
            for (int r = 0; r < 2; ++r) {                                          \
                float4 w_ = wreg[r];                                               \
                *(float4*)&Bs[((tid >> 4) + 16 * r) * 68 + (tid & 15) * 4] =       \
                    make_float4(signf_of(w_.x), signf_of(w_.y),                    \
                                signf_of(w_.z), signf_of(w_.w));                   \
            }                                                                      \
            *(u16x8*)&Bt[(tid >> 2) * 40 + (tid & 3) * 8] = btreg;                 \
        }

    ISSUE_LOADS(0);
    WRITE_LDS();
    __syncthreads();

    for (int s = 0; s < NSTAGE; ++s) {
        if (s + 1 < NSTAGE) ISSUE_LOADS(s + 1);   // T14: in flight across compute

        // ---- base GEMM on the matrix pipe ----
        {
            bf16x8 af0 = *(const bf16x8*)&baseA[(wv * 32 +      r16) * 40 + g * 8];
            bf16x8 af1 = *(const bf16x8*)&baseA[(wv * 32 + 16 + r16) * 40 + g * 8];
            #pragma unroll
            for (int tc = 0; tc < 4; ++tc) {
                bf16x8 bf = *(const bf16x8*)&Bt[(tc * 16 + r16) * 40 + g * 8];
                acc[0][tc] = __builtin_amdgcn_mfma_f32_16x16x32_bf16(af0, bf, acc[0][tc], 0, 0, 0);
                acc[1][tc] = __builtin_amdgcn_mfma_f32_16x16x32_bf16(af1, bf, acc[1][tc], 0, 0, 0);
            }
        }

        // ---- acid chain: 32 ascending k, bit-identical to R9/R13 ----
        #pragma unroll 8
        for (int k = 0; k < BK; ++k) {
            const float4 pa = *(const float4*)&As_acid[k * 132 + ty * 8];
            const float4 pb = *(const float4*)&As_acid[k * 132 + ty * 8 + 4];
            const float4 sv = *(const float4*)&Bs[k * 68 + tx * 4];
            const float av[8] = {pa.x, pa.y, pa.z, pa.w, pb.x, pb.y, pb.z, pb.w};
            const float sn[4] = {sv.x, sv.y, sv.z, sv.w};
            #pragma unroll
            for (int m = 0; m < 8; ++m)
                #pragma unroll
                for (int n = 0; n < 4; ++n)
                    ca[m][n] = fmaf(av[m], sn[n], ca[m][n]);
        }

        if (((s + 1) & 15) == 0) {     // panel fold every 512 k
            #pragma unroll
            for (int m = 0; m < 8; ++m)
                #pragma unroll
                for (int n = 0; n < 4; ++n) {
                    ma[m][n] += ca[m][n]; ca[m][n] = 0.f;
                }
        }

        __syncthreads();
        if (s + 1 < NSTAGE) WRITE_LDS();
        __syncthreads();
    }

    // ---- combine base frags + epilogue (R13-verified layout) ----
    #pragma unroll
    for (int tr = 0; tr < 2; ++tr)
        #pragma unroll
        for (int tc = 0; tc < 4; ++tc)
            #pragma unroll
            for (int rr = 0; rr < 4; ++rr)
                Bout[(wv * 32 + tr * 16 + g * 4 + rr) * 68 + tc * 16 + r16] = acc[tr][tc][rr];
    __syncthreads();

    #pragma unroll
    for (int m = 0; m < 8; ++m) {
        int row = ty * 8 + m;
        const float4 bv = *(const float4*)&Bout[row * 68 + tx * 4];
        const float bb[4] = {bv.x, bv.y, bv.z, bv.w};
        #pragma unroll
        for (int n = 0; n < 4; ++n) {
            float r    = ma[m][n] - bb[n];
            float conc = fabsf(r) / 409.6f;
            float hc   = (r < 0.f) ? (1e-14f / conc) : conc;
            float ph   = (-logf(hc)) / 2.302585092994046f;
            out[(size_t)(bm0 + row) * NOUT + bn0 + tx * 4 + n] = ph;
        }
    }
    #undef ISSUE_LOADS
    #undef WRITE_LDS
}

// Fallback (ws too small): R9's proven all-VALU kernel, on-the-fly terms.
__global__ __launch_bounds__(256, 2) void acid_gemm_fly(const float* __restrict__ X,
                                                        const float* __restrict__ W,
                                                        float* __restrict__ out) {
    __shared__ float2 Asf[BK][BM + 2];
    __shared__ float  Bsf[BK][BN];
    const int tid = threadIdx.x;
    const int tx = tid & 15, ty = tid >> 4;
    const int bm0 = blockIdx.y * BM, bn0 = blockIdx.x * BN;
    float ma[8][4] = {}, mb[8][4] = {}, ca[8][4] = {}, cb[8][4] = {};
    for (int s = 0; s < NSTAGE; ++s) {
        const int k0 = s * BK;
        for (int idx = tid; idx < BM * BK; idx += 256) {
            int m = idx >> 5, k = idx & 31;
            Asf[k][m] = compute_terms(X[(size_t)(bm0 + m) * NIN + k0 + k]);
        }
        for (int idx = tid; idx < BK * BN; idx += 256) {
            int k = idx >> 6, c = idx & 63;
            Bsf[k][c] = signf_of(W[(size_t)(k0 + k) * NOUT + bn0 + c]);
        }
        __syncthreads();
        #pragma unroll 4
        for (int k = 0; k < BK; ++k) {
            float2 av[8]; float sv[4];
            #pragma unroll
            for (int m = 0; m < 8; ++m) av[m] = Asf[k][ty * 8 + m];
            #pragma unroll
            for (int n = 0; n < 4; ++n) sv[n] = Bsf[k][tx * 4 + n];
            #pragma unroll
            for (int m = 0; m < 8; ++m)
                #pragma unroll
                for (int n = 0; n < 4; ++n) {
                    ca[m][n] = fmaf(av[m].x, sv[n], ca[m][n]);
                    cb[m][n] = fmaf(av[m].y, sv[n], cb[m][n]);
                }
        }
        if (((s + 1) & 15) == 0) {
            #pragma unroll
            for (int m = 0; m < 8; ++m)
                #pragma unroll
                for (int n = 0; n < 4; ++n) {
                    ma[m][n] += ca[m][n]; ca[m][n] = 0.f;
                    mb[m][n] += cb[m][n]; cb[m][n] = 0.f;
                }
        }
        __syncthreads();
    }
    #pragma unroll
    for (int m = 0; m < 8; ++m) {
        int row = bm0 + ty * 8 + m;
        #pragma unroll
        for (int n = 0; n < 4; ++n) {
            int col = bn0 + tx * 4 + n;
            float r = ma[m][n] - mb[m][n];
            float conc = fabsf(r) / 409.6f;
            float hc = (r < 0.f) ? (1e-14f / conc) : conc;
            out[(size_t)row * NOUT + col] = (-logf(hc)) / 2.302585092994046f;
        }
    }
}

extern "C" void kernel_launch(void* const* d_in, const int* in_sizes, int n_in,
                              void* d_out, int out_size, void* d_ws, size_t ws_size,
                              hipStream_t stream) {
    const float* x = (const float*)d_in[0];
    const float* w = (const float*)d_in[1];
    float* out = (float*)d_out;

    const size_t nElem  = (size_t)BATCH * NIN;
    const size_t needWs = nElem * 4 + nElem * 2 + nElem * 2;   // AaT + Ab + signT = 134.2 MB
    dim3 grid(NOUT / BN, BATCH / BM);

    if (ws_size >= needWs) {
        float*          aaT   = (float*)d_ws;
        unsigned short* ab    = (unsigned short*)((char*)d_ws + nElem * 4);
        unsigned short* signT = (unsigned short*)((char*)d_ws + nElem * 6);
        precompute_A    <<<dim3(64, 64), 256, 0, stream>>>(x, aaT, ab);
        precompute_signT<<<dim3(64, 64), 256, 0, stream>>>(w, signT);
        acid_gemm_hyb   <<<grid, dim3(256), 0, stream>>>(aaT, ab, signT, w, out);
    } else {
        acid_gemm_fly<<<grid, dim3(256), 0, stream>>>(x, w, out);
    }
}

// Round 15
// 2162.454 us; speedup vs baseline: 1.1508x; 1.1508x over previous
//
#include <hip/hip_runtime.h>
#include <math.h>

#define BATCH 4096
#define NIN   4096
#define NOUT  4096

#define BM 128
#define BN 128
#define BK 32
#define NSTAGE (NIN / BK)        // 128
// R9-verified ACID ORDER (frozen): [512x8] k-panels, single ascending fmaf
// chain, fold every 16 stages, f32 epilogue. BASE on MFMA pipe (R13-verified).
// R15: 8x8 per-thread acid tile (BN 64->128) halves DS-reads per fma.

typedef __attribute__((ext_vector_type(8))) short bf16x8;
typedef __attribute__((ext_vector_type(8))) unsigned short u16x8;
typedef __attribute__((ext_vector_type(4))) float f32x4;

__device__ __forceinline__ float2 compute_terms(float xv) {
    float h  = (float)exp10(-(double)xv);
    float oh = 1e-14f / h;
    return make_float2(h * 0.1f, oh * 0.1f);
}
__device__ __forceinline__ unsigned short bf16_rne(float v) {
    unsigned int b = __float_as_uint(v);
    return (unsigned short)((b + 0x7FFFu + ((b >> 16) & 1u)) >> 16);
}
__device__ __forceinline__ float signf_of(float wv) {
    return (wv > 0.f) ? 1.f : ((wv < 0.f) ? -1.f : 0.f);
}
__device__ __forceinline__ unsigned short signbf16_of(float wv) {
    return (wv > 0.f) ? 0x3F80u : ((wv < 0.f) ? 0xBF80u : 0u);
}

// --- precompute A: acid f32 TRANSPOSED AaT[k][m] (LDS-tiled) + base bf16 Ab[m][k] ---
__global__ __launch_bounds__(256) void precompute_A(const float* __restrict__ x,
                                                    float* __restrict__ aaT,
                                                    unsigned short* __restrict__ ab) {
    __shared__ float tile[64][65];
    const int m0 = blockIdx.y * 64, k0 = blockIdx.x * 64;
    const int tid = threadIdx.x;
    #pragma unroll
    for (int it = 0; it < 4; ++it) {
        int idx = tid + it * 256;
        int row = idx >> 4, q = idx & 15;
        float4 xv = *(const float4*)(x + (size_t)(m0 + row) * NIN + k0 + q * 4);
        float2 t0 = compute_terms(xv.x), t1 = compute_terms(xv.y),
               t2 = compute_terms(xv.z), t3 = compute_terms(xv.w);
        *(ushort4*)(ab + (size_t)(m0 + row) * NIN + k0 + q * 4) =
            make_ushort4(bf16_rne(t0.y), bf16_rne(t1.y), bf16_rne(t2.y), bf16_rne(t3.y));
        tile[row][q * 4 + 0] = t0.x; tile[row][q * 4 + 1] = t1.x;
        tile[row][q * 4 + 2] = t2.x; tile[row][q * 4 + 3] = t3.x;
    }
    __syncthreads();
    #pragma unroll
    for (int it = 0; it < 4; ++it) {
        int idx = tid + it * 256;
        int krow = idx >> 4, q = idx & 15;
        float4 v = make_float4(tile[q * 4 + 0][krow], tile[q * 4 + 1][krow],
                               tile[q * 4 + 2][krow], tile[q * 4 + 3][krow]);
        *(float4*)(aaT + (size_t)(k0 + krow) * NIN + m0 + q * 4) = v;
    }
}

// --- precompute W: sign bf16 TRANSPOSED signT[n][k] (LDS-tiled) ---
__global__ __launch_bounds__(256) void precompute_signT(const float* __restrict__ w,
                                                        unsigned short* __restrict__ sT) {
    __shared__ unsigned short tile[64][68];
    const int k0 = blockIdx.y * 64, n0 = blockIdx.x * 64;
    const int tid = threadIdx.x;
    #pragma unroll
    for (int it = 0; it < 4; ++it) {
        int idx = tid + it * 256;
        int krow = idx >> 4, q = idx & 15;
        float4 wv = *(const float4*)(w + (size_t)(k0 + krow) * NOUT + n0 + q * 4);
        *(ushort4*)&tile[krow][q * 4] =
            make_ushort4(signbf16_of(wv.x), signbf16_of(wv.y), signbf16_of(wv.z), signbf16_of(wv.w));
    }
    __syncthreads();
    #pragma unroll
    for (int it = 0; it < 2; ++it) {
        int idx = tid + it * 256;
        int n = idx >> 3, kc = idx & 7;
        u16x8 v;
        #pragma unroll
        for (int j = 0; j < 8; ++j) v[j] = tile[kc * 8 + j][n];
        *(u16x8*)(sT + (size_t)(n0 + n) * NIN + k0 + kc * 8) = v;
    }
}

// LDS plan (union, 67584 B -> 2 blocks/CU at 135 KiB):
//   As_acid [32][132] f32 @0      (16896)  acid A [k][m]
//   Bs      [32][132] f32 @16896  (16896)  sign(W) f32 [k][n], n split {0..63|64..127}
//   baseA   [128][40] u16 @33792  (10240)  base A bf16 [m][k]
//   Bt      [128][40] u16 @44032  (10240)  sign bf16 [n][k]
//   Bout    [128][132] f32 @0     (67584)  base result (post-loop reuse)
#define OFF_BS 16896
#define OFF_BA 33792
#define OFF_BT 44032

__global__ __launch_bounds__(256, 2) void acid_gemm_hyb(const float* __restrict__ AaT,
                                                        const unsigned short* __restrict__ Ab,
                                                        const unsigned short* __restrict__ SignT,
                                                        const float* __restrict__ W,
                                                        float* __restrict__ out) {
    __shared__ __align__(16) char smem[67584];
    float*          As_acid = (float*)smem;
    float*          Bs      = (float*)(smem + OFF_BS);
    unsigned short* baseA   = (unsigned short*)(smem + OFF_BA);
    unsigned short* Bt      = (unsigned short*)(smem + OFF_BT);
    float*          Bout    = (float*)smem;

    const int tid  = threadIdx.x;
    const int tx   = tid & 15;     // acid cols: tx*4..+3 and 64+tx*4..+3
    const int ty   = tid >> 4;     // acid rows ty*8..+7
    const int lane = tid & 63;
    const int wv   = tid >> 6;
    const int g    = lane >> 4;
    const int r16  = lane & 15;
    const int bm0  = blockIdx.y * BM;
    const int bn0  = blockIdx.x * BN;

    float ma[8][8] = {}, ca[8][8] = {};
    f32x4 acc[2][8] = {};

    float4 areg[4];      // AaT: k-row tid>>3, m-quads (tid&7)+8r
    u16x8  breg[2];      // Ab: rows (tid>>2)+64r, chunk tid&3
    float4 wreg[2][2];   // W: k rows (tid>>4)+16r, halves h*64, col-quad tid&15
    u16x8  btreg[2];     // SignT: rows (tid>>2)+64r, chunk tid&3

    #define ISSUE_LOADS(s)                                                         \
        {                                                                          \
            const int k0_ = (s) * BK;                                              \
            _Pragma("unroll")                                                      \
            for (int r = 0; r < 4; ++r)                                            \
                areg[r] = *(const float4*)(AaT +                                   \
                    (size_t)(k0_ + (tid >> 3)) * NIN + bm0 + ((tid & 7) + 8 * r) * 4);\
            _Pragma("unroll")                                                      \
            for (int r = 0; r < 2; ++r)                                            \
                breg[r] = *(const u16x8*)(Ab +                                     \
                    (size_t)(bm0 + (tid >> 2) + 64 * r) * NIN + k0_ + (tid & 3) * 8);\
            _Pragma("unroll")                                                      \
            for (int r = 0; r < 2; ++r)                                            \
                _Pragma("unroll")                                                  \
                for (int h = 0; h < 2; ++h)                                        \
                    wreg[r][h] = *(const float4*)(W +                              \
                        (size_t)(k0_ + (tid >> 4) + 16 * r) * NOUT + bn0 + h * 64 + (tid & 15) * 4);\
            _Pragma("unroll")                                                      \
            for (int r = 0; r < 2; ++r)                                            \
                btreg[r] = *(const u16x8*)(SignT +                                 \
                    (size_t)(bn0 + (tid >> 2) + 64 * r) * NIN + k0_ + (tid & 3) * 8);\
        }

    #define WRITE_LDS()                                                            \
        {                                                                          \
            _Pragma("unroll")                                                      \
            for (int r = 0; r < 4; ++r)                                            \
                *(float4*)&As_acid[(tid >> 3) * 132 + ((tid & 7) + 8 * r) * 4] = areg[r];\
            _Pragma("unroll")                                                      \
            for (int r = 0; r < 2; ++r)                                            \
                *(u16x8*)&baseA[((tid >> 2) + 64 * r) * 40 + (tid & 3) * 8] = breg[r];\
            _Pragma("unroll")                                                      \
            for (int r = 0; r < 2; ++r)                                            \
                _Pragma("unroll")                                                  \
                for (int h = 0; h < 2; ++h) {                                      \
                    float4 w_ = wreg[r][h];                                        \
                    *(float4*)&Bs[((tid >> 4) + 16 * r) * 132 + h * 64 + (tid & 15) * 4] = \
                        make_float4(signf_of(w_.x), signf_of(w_.y),                \
                                    signf_of(w_.z), signf_of(w_.w));               \
                }                                                                  \
            _Pragma("unroll")                                                      \
            for (int r = 0; r < 2; ++r)                                            \
                *(u16x8*)&Bt[((tid >> 2) + 64 * r) * 40 + (tid & 3) * 8] = btreg[r];\
        }

    ISSUE_LOADS(0);
    WRITE_LDS();
    __syncthreads();

    for (int s = 0; s < NSTAGE; ++s) {
        if (s + 1 < NSTAGE) ISSUE_LOADS(s + 1);   // T14: in flight across compute

        // ---- base GEMM on the matrix pipe ----
        {
            bf16x8 af0 = *(const bf16x8*)&baseA[(wv * 32 +      r16) * 40 + g * 8];
            bf16x8 af1 = *(const bf16x8*)&baseA[(wv * 32 + 16 + r16) * 40 + g * 8];
            #pragma unroll
            for (int tc = 0; tc < 8; ++tc) {
                bf16x8 bf = *(const bf16x8*)&Bt[(tc * 16 + r16) * 40 + g * 8];
                acc[0][tc] = __builtin_amdgcn_mfma_f32_16x16x32_bf16(af0, bf, acc[0][tc], 0, 0, 0);
                acc[1][tc] = __builtin_amdgcn_mfma_f32_16x16x32_bf16(af1, bf, acc[1][tc], 0, 0, 0);
            }
        }

        // ---- acid chain: 32 ascending k, bit-identical order to R9/R14 ----
        #pragma unroll 4
        for (int k = 0; k < BK; ++k) {
            const float4 pa = *(const float4*)&As_acid[k * 132 + ty * 8];
            const float4 pb = *(const float4*)&As_acid[k * 132 + ty * 8 + 4];
            const float4 s0 = *(const float4*)&Bs[k * 132 + tx * 4];
            const float4 s1 = *(const float4*)&Bs[k * 132 + 64 + tx * 4];
            const float av[8] = {pa.x, pa.y, pa.z, pa.w, pb.x, pb.y, pb.z, pb.w};
            const float sn[8] = {s0.x, s0.y, s0.z, s0.w, s1.x, s1.y, s1.z, s1.w};
            #pragma unroll
            for (int m = 0; m < 8; ++m)
                #pragma unroll
                for (int n = 0; n < 8; ++n)
                    ca[m][n] = fmaf(av[m], sn[n], ca[m][n]);
        }

        if (((s + 1) & 15) == 0) {     // panel fold every 512 k
            #pragma unroll
            for (int m = 0; m < 8; ++m)
                #pragma unroll
                for (int n = 0; n < 8; ++n) {
                    ma[m][n] += ca[m][n]; ca[m][n] = 0.f;
                }
        }

        __syncthreads();
        if (s + 1 < NSTAGE) WRITE_LDS();
        __syncthreads();
    }

    // ---- combine base frags + epilogue ----
    #pragma unroll
    for (int tr = 0; tr < 2; ++tr)
        #pragma unroll
        for (int tc = 0; tc < 8; ++tc)
            #pragma unroll
            for (int rr = 0; rr < 4; ++rr)
                Bout[(wv * 32 + tr * 16 + g * 4 + rr) * 132 + tc * 16 + r16] = acc[tr][tc][rr];
    __syncthreads();

    #pragma unroll
    for (int m = 0; m < 8; ++m) {
        int row = ty * 8 + m;
        const float4 bv0 = *(const float4*)&Bout[row * 132 + tx * 4];
        const float4 bv1 = *(const float4*)&Bout[row * 132 + 64 + tx * 4];
        const float bb[8] = {bv0.x, bv0.y, bv0.z, bv0.w, bv1.x, bv1.y, bv1.z, bv1.w};
        #pragma unroll
        for (int n = 0; n < 8; ++n) {
            int col = bn0 + (n < 4 ? tx * 4 + n : 64 + tx * 4 + (n - 4));
            float r    = ma[m][n] - bb[n];
            float conc = fabsf(r) / 409.6f;
            float hc   = (r < 0.f) ? (1e-14f / conc) : conc;
            float ph   = (-logf(hc)) / 2.302585092994046f;
            out[(size_t)(bm0 + row) * NOUT + col] = ph;
        }
    }
    #undef ISSUE_LOADS
    #undef WRITE_LDS
}

// Fallback (ws too small): R9's proven all-VALU kernel, on-the-fly terms.
__global__ __launch_bounds__(256, 2) void acid_gemm_fly(const float* __restrict__ X,
                                                        const float* __restrict__ W,
                                                        float* __restrict__ out) {
    __shared__ float2 Asf[BK][128 + 2];
    __shared__ float  Bsf[BK][64];
    const int tid = threadIdx.x;
    const int tx = tid & 15, ty = tid >> 4;
    const int bm0 = blockIdx.y * 128, bn0 = blockIdx.x * 64;
    float ma[8][4] = {}, mb[8][4] = {}, ca[8][4] = {}, cb[8][4] = {};
    for (int s = 0; s < NSTAGE; ++s) {
        const int k0 = s * BK;
        for (int idx = tid; idx < 128 * BK; idx += 256) {
            int m = idx >> 5, k = idx & 31;
            Asf[k][m] = compute_terms(X[(size_t)(bm0 + m) * NIN + k0 + k]);
        }
        for (int idx = tid; idx < BK * 64; idx += 256) {
            int k = idx >> 6, c = idx & 63;
            Bsf[k][c] = signf_of(W[(size_t)(k0 + k) * NOUT + bn0 + c]);
        }
        __syncthreads();
        #pragma unroll 4
        for (int k = 0; k < BK; ++k) {
            float2 av[8]; float sv[4];
            #pragma unroll
            for (int m = 0; m < 8; ++m) av[m] = Asf[k][ty * 8 + m];
            #pragma unroll
            for (int n = 0; n < 4; ++n) sv[n] = Bsf[k][tx * 4 + n];
            #pragma unroll
            for (int m = 0; m < 8; ++m)
                #pragma unroll
                for (int n = 0; n < 4; ++n) {
                    ca[m][n] = fmaf(av[m].x, sv[n], ca[m][n]);
                    cb[m][n] = fmaf(av[m].y, sv[n], cb[m][n]);
                }
        }
        if (((s + 1) & 15) == 0) {
            #pragma unroll
            for (int m = 0; m < 8; ++m)
                #pragma unroll
                for (int n = 0; n < 4; ++n) {
                    ma[m][n] += ca[m][n]; ca[m][n] = 0.f;
                    mb[m][n] += cb[m][n]; cb[m][n] = 0.f;
                }
        }
        __syncthreads();
    }
    #pragma unroll
    for (int m = 0; m < 8; ++m) {
        int row = bm0 + ty * 8 + m;
        #pragma unroll
        for (int n = 0; n < 4; ++n) {
            int col = bn0 + tx * 4 + n;
            float r = ma[m][n] - mb[m][n];
            float conc = fabsf(r) / 409.6f;
            float hc = (r < 0.f) ? (1e-14f / conc) : conc;
            out[(size_t)row * NOUT + col] = (-logf(hc)) / 2.302585092994046f;
        }
    }
}

extern "C" void kernel_launch(void* const* d_in, const int* in_sizes, int n_in,
                              void* d_out, int out_size, void* d_ws, size_t ws_size,
                              hipStream_t stream) {
    const float* x = (const float*)d_in[0];
    const float* w = (const float*)d_in[1];
    float* out = (float*)d_out;

    const size_t nElem  = (size_t)BATCH * NIN;
    const size_t needWs = nElem * 4 + nElem * 2 + nElem * 2;   // AaT + Ab + signT = 134.2 MB
    dim3 grid(NOUT / BN, BATCH / BM);

    if (ws_size >= needWs) {
        float*          aaT   = (float*)d_ws;
        unsigned short* ab    = (unsigned short*)((char*)d_ws + nElem * 4);
        unsigned short* signT = (unsigned short*)((char*)d_ws + nElem * 6);
        precompute_A    <<<dim3(64, 64), 256, 0, stream>>>(x, aaT, ab);
        precompute_signT<<<dim3(64, 64), 256, 0, stream>>>(w, signT);
        acid_gemm_hyb   <<<grid, dim3(256), 0, stream>>>(aaT, ab, signT, w, out);
    } else {
        acid_gemm_fly<<<dim3(NOUT / 64, BATCH / 128), dim3(256), 0, stream>>>(x, w, out);
    }
}